// Round 6
// baseline (60.834 us; speedup 1.0000x reference)
//
#include <hip/hip_runtime.h>

#define FH 128
#define FW 128
#define CPLANE 490          // 10*7*7 input channels; plane c_in serves bin (ph,pw)
#define NBATCH 4
#define SSCALE 0.0625f

// ---- kernel A: bucket roi indices by batch into d_ws -----------------------
// ws layout: ws[0..3] = counts, ws[4 + b*R + slot] = roi index
__global__ __launch_bounds__(1024) void bucket_rois(const float* __restrict__ rois,
                                                    int R, int* __restrict__ ws) {
    __shared__ int cnt[NBATCH];
    if (threadIdx.x < NBATCH) cnt[threadIdx.x] = 0;
    __syncthreads();
    for (int i = threadIdx.x; i < R; i += blockDim.x) {
        int b = (int)rois[(size_t)i * 5];
        int slot = atomicAdd(&cnt[b], 1);
        ws[NBATCH + b * R + slot] = i;
    }
    __syncthreads();
    if (threadIdx.x < NBATCH) ws[threadIdx.x] = cnt[threadIdx.x];
}

// ---- kernel B: one block per (c_in, b) plane; gather via L1/L2 -------------
// Block's entire working set = one 64KB plane -> first touch HBM, reuse hits
// L1/L2. No LDS, no barriers; latency hidden by ~31 resident waves/CU.
__global__ __launch_bounds__(256) void psroi_plane(const float* __restrict__ feat,
                                                   const float* __restrict__ rois,
                                                   const int* __restrict__ ws,
                                                   float* __restrict__ out, int R) {
    const int c_in = blockIdx.x;
    const int b    = blockIdx.y;
    const int pw   = c_in % 7;
    const int ph   = (c_in / 7) % 7;

    const int  nb   = ws[b];
    const int* list = ws + NBATCH + b * R;
    const float* __restrict__ fp = feat + ((size_t)b * CPLANE + c_in) * (FH * FW);

    const int   sub = threadIdx.x & 3;           // bilinear sample id (iy,ix)
    const float sy  = 0.25f + 0.5f * (float)(sub >> 1);
    const float sx  = 0.25f + 0.5f * (float)(sub & 1);

    for (int base = 0; base < nb; base += 64) {
        const int k = base + (threadIdx.x >> 2);
        if (k >= nb) break;
        const int ri = list[k];

        const float* roi = rois + (size_t)ri * 5;
        const float x1 = roi[1] * SSCALE;
        const float y1 = roi[2] * SSCALE;
        const float bw = fmaxf(roi[3] * SSCALE - x1, 0.1f) * (1.0f / 7.0f);
        const float bh = fmaxf(roi[4] * SSCALE - y1, 0.1f) * (1.0f / 7.0f);

        float y = y1 + ((float)ph + sy) * bh;
        y = fminf(fmaxf(y, 0.0f), 127.0f);
        float y0f = floorf(y);
        int   y0  = (int)y0f;
        float ly  = y - y0f;
        if (y0 > 126) { y0 = 126; ly = 1.0f; }   // y==127 -> full weight on row 127

        float x = x1 + ((float)pw + sx) * bw;
        x = fminf(fmaxf(x, 0.0f), 127.0f);
        float x0f = floorf(x);
        int   x0  = (int)x0f;
        float lx  = x - x0f;
        if (x0 > 126) { x0 = 126; lx = 1.0f; }

        const float* p = fp + y0 * FW + x0;
        float2 top2, bot2;
        __builtin_memcpy(&top2, p,      sizeof(float2));
        __builtin_memcpy(&bot2, p + FW, sizeof(float2));

        const float top = top2.x + (top2.y - top2.x) * lx;
        const float bot = bot2.x + (bot2.y - bot2.x) * lx;
        float val = top + (bot - top) * ly;

        // reduce the 4 samples of this roi's bin, average
        val += __shfl_xor(val, 1);
        val += __shfl_xor(val, 2);
        if (sub == 0) out[(size_t)ri * CPLANE + c_in] = val * 0.25f;
    }
}

extern "C" void kernel_launch(void* const* d_in, const int* in_sizes, int n_in,
                              void* d_out, int out_size, void* d_ws, size_t ws_size,
                              hipStream_t stream) {
    const float* feat = (const float*)d_in[0];
    const float* rois = (const float*)d_in[1];
    float* out = (float*)d_out;
    int* ws = (int*)d_ws;

    const int R = in_sizes[1] / 5;   // 2048

    bucket_rois<<<1, 1024, 0, stream>>>(rois, R, ws);

    dim3 grid(CPLANE, NBATCH);       // (490, 4) -> 1960 blocks, ~all co-resident
    psroi_plane<<<grid, 256, 0, stream>>>(feat, rois, ws, out, R);
}

// Round 8
// 40.003 us; speedup vs baseline: 1.5208x; 1.5208x over previous
//
#include <hip/hip_runtime.h>

#define FH 128
#define FW 128
#define CPLANE 490                 // 10*7*7 input channels; plane c_in serves bin (ph,pw)
#define NBATCH 4
#define NPLANES (NBATCH * CPLANE)  // 1960
#define SSCALE 0.0625f

// ---- kernel A: bucket roi indices by batch into d_ws -----------------------
// ws layout (proven safe, 8.2 KB): ws[0..3]=counts, ws[4 + b*R + slot]=roi idx
__global__ __launch_bounds__(1024) void bucket_rois(const float* __restrict__ rois,
                                                    int R, int* __restrict__ ws) {
    __shared__ int cnt[NBATCH];
    if (threadIdx.x < NBATCH) cnt[threadIdx.x] = 0;
    __syncthreads();
    for (int i = threadIdx.x; i < R; i += blockDim.x) {
        int b = (int)rois[(size_t)i * 5];
        int slot = atomicAdd(&cnt[b], 1);
        ws[NBATCH + b * R + slot] = i;
    }
    __syncthreads();
    if (threadIdx.x < NBATCH) ws[threadIdx.x] = cnt[threadIdx.x];
}

// ---- kernel B: one plane per block, staged in LDS ---------------------------
// 1024 threads, 64 KB LDS -> 2 blocks/CU = 32 waves/CU: while one block waits
// at its staging barrier, the co-resident block's waves gather from LDS.
__global__ __launch_bounds__(1024) void psroi_plane_lds(const float* __restrict__ feat,
                                                        const float* __restrict__ rois,
                                                        const int* __restrict__ ws,
                                                        float* __restrict__ out, int R) {
    __shared__ float plane[FH * FW];   // exactly 64 KB (static limit, proven in round 4)
    const int tid  = threadIdx.x;
    const int pl   = blockIdx.x;                 // == b*CPLANE + c_in (feat plane order)
    const int b    = pl / CPLANE;
    const int c_in = pl - b * CPLANE;

    // ---- stage plane: 4 coalesced float4 per thread ----
    const float* __restrict__ src = feat + (size_t)pl * (FH * FW);
    float4 s0 = *(const float4*)(src + (0 * 1024 + tid) * 4);
    float4 s1 = *(const float4*)(src + (1 * 1024 + tid) * 4);
    float4 s2 = *(const float4*)(src + (2 * 1024 + tid) * 4);
    float4 s3 = *(const float4*)(src + (3 * 1024 + tid) * 4);
    *(float4*)(plane + (0 * 1024 + tid) * 4) = s0;
    *(float4*)(plane + (1 * 1024 + tid) * 4) = s1;
    *(float4*)(plane + (2 * 1024 + tid) * 4) = s2;
    *(float4*)(plane + (3 * 1024 + tid) * 4) = s3;
    __syncthreads();

    // ---- gather: 4 lanes per roi (one per bilinear sample) ----
    const int pw = c_in % 7;
    const int ph = (c_in / 7) % 7;
    const int  nb   = ws[b];
    const int* list = ws + NBATCH + b * R;

    const int   sub = tid & 3;
    const float sy  = 0.25f + 0.5f * (float)(sub >> 1);
    const float sx  = 0.25f + 0.5f * (float)(sub & 1);

    for (int base = 0; base < nb; base += 256) {
        const int k = base + (tid >> 2);
        if (k < nb) {
            const int ri = list[k];
            const float* roi = rois + (size_t)ri * 5;   // hot 40 KB, L1/L2-resident
            const float x1 = roi[1] * SSCALE;
            const float y1 = roi[2] * SSCALE;
            const float bw = fmaxf(roi[3] * SSCALE - x1, 0.1f) * (1.0f / 7.0f);
            const float bh = fmaxf(roi[4] * SSCALE - y1, 0.1f) * (1.0f / 7.0f);

            float y = y1 + ((float)ph + sy) * bh;
            y = fminf(fmaxf(y, 0.0f), 127.0f);
            float y0f = floorf(y);
            int   y0  = (int)y0f;
            float ly  = y - y0f;
            if (y0 > 126) { y0 = 126; ly = 1.0f; }   // y==127 -> full weight on row 127

            float x = x1 + ((float)pw + sx) * bw;
            x = fminf(fmaxf(x, 0.0f), 127.0f);
            float x0f = floorf(x);
            int   x0  = (int)x0f;
            float lx  = x - x0f;
            if (x0 > 126) { x0 = 126; lx = 1.0f; }

            const float* p = plane + y0 * FW + x0;
            const float v00 = p[0];
            const float v01 = p[1];
            const float v10 = p[FW];
            const float v11 = p[FW + 1];

            const float top = v00 + (v01 - v00) * lx;
            const float bot = v10 + (v11 - v10) * lx;
            float val = top + (bot - top) * ly;

            val += __shfl_xor(val, 1);
            val += __shfl_xor(val, 2);
            if (sub == 0) out[(size_t)ri * CPLANE + c_in] = val * 0.25f;
        }
    }
}

extern "C" void kernel_launch(void* const* d_in, const int* in_sizes, int n_in,
                              void* d_out, int out_size, void* d_ws, size_t ws_size,
                              hipStream_t stream) {
    const float* feat = (const float*)d_in[0];
    const float* rois = (const float*)d_in[1];
    float* out = (float*)d_out;
    int* ws = (int*)d_ws;

    const int R = in_sizes[1] / 5;   // 2048

    bucket_rois<<<1, 1024, 0, stream>>>(rois, R, ws);
    psroi_plane_lds<<<NPLANES, 1024, 0, stream>>>(feat, rois, ws, out, R);
}

// Round 9
// 35.582 us; speedup vs baseline: 1.7097x; 1.1243x over previous
//
#include <hip/hip_runtime.h>

#define FH 128
#define FW 128
#define CPLANE 490                 // 10*7*7 input channels; plane c_in serves bin (ph,pw)
#define NBATCH 4
#define NPLANES (NBATCH * CPLANE)  // 1960 = 8 * 245
#define SSCALE 0.0625f

typedef float f32x4 __attribute__((ext_vector_type(4)));

// ---- kernel A: bucket roi indices by batch into d_ws -----------------------
// ws layout (proven safe, 8.2 KB): ws[0..3]=counts, ws[4 + b*R + slot]=roi idx
__global__ __launch_bounds__(1024) void bucket_rois(const float* __restrict__ rois,
                                                    int R, int* __restrict__ ws) {
    __shared__ int cnt[NBATCH];
    if (threadIdx.x < NBATCH) cnt[threadIdx.x] = 0;
    __syncthreads();
    for (int i = threadIdx.x; i < R; i += blockDim.x) {
        int b = (int)rois[(size_t)i * 5];
        int slot = atomicAdd(&cnt[b], 1);
        ws[NBATCH + b * R + slot] = i;
    }
    __syncthreads();
    if (threadIdx.x < NBATCH) ws[threadIdx.x] = cnt[threadIdx.x];
}

// ---- kernel B: one plane per block, staged in LDS ---------------------------
// XCD-chunked swizzle: sibling planes (c_in..c_in+15 share each 64B out-line)
// run on the SAME XCD close in time -> stores merge in its L2 (write-amp fix).
// NT staging loads keep the 128MB one-pass feature stream from evicting the
// pending out-lines.
__global__ __launch_bounds__(1024) void psroi_plane_lds(const float* __restrict__ feat,
                                                        const float* __restrict__ rois,
                                                        const int* __restrict__ ws,
                                                        float* __restrict__ out, int R) {
    __shared__ float plane[FH * FW];   // exactly 64 KB -> 2 blocks/CU, 32 waves/CU
    const int tid = threadIdx.x;
    const int bid = blockIdx.x;
    const int pl  = (bid & 7) * (NPLANES / 8) + (bid >> 3);  // bijective XCD chunking
    const int b    = pl / CPLANE;
    const int c_in = pl - b * CPLANE;

    // ---- stage plane: 4 coalesced nontemporal float4 per thread ----
    const f32x4* __restrict__ src = (const f32x4*)(feat + (size_t)pl * (FH * FW));
    f32x4 s0 = __builtin_nontemporal_load(src + 0 * 1024 + tid);
    f32x4 s1 = __builtin_nontemporal_load(src + 1 * 1024 + tid);
    f32x4 s2 = __builtin_nontemporal_load(src + 2 * 1024 + tid);
    f32x4 s3 = __builtin_nontemporal_load(src + 3 * 1024 + tid);
    *(f32x4*)(plane + (0 * 1024 + tid) * 4) = s0;
    *(f32x4*)(plane + (1 * 1024 + tid) * 4) = s1;
    *(f32x4*)(plane + (2 * 1024 + tid) * 4) = s2;
    *(f32x4*)(plane + (3 * 1024 + tid) * 4) = s3;
    __syncthreads();

    // ---- gather: 4 lanes per roi (one per bilinear sample) ----
    const int pw = c_in % 7;
    const int ph = (c_in / 7) % 7;
    const int  nb   = ws[b];
    const int* list = ws + NBATCH + b * R;

    const int   sub = tid & 3;
    const float sy  = 0.25f + 0.5f * (float)(sub >> 1);
    const float sx  = 0.25f + 0.5f * (float)(sub & 1);

    for (int base = 0; base < nb; base += 256) {
        const int k = base + (tid >> 2);
        if (k < nb) {
            const int ri = list[k];
            const float* roi = rois + (size_t)ri * 5;   // hot 40 KB, cache-resident
            const float x1 = roi[1] * SSCALE;
            const float y1 = roi[2] * SSCALE;
            const float bw = fmaxf(roi[3] * SSCALE - x1, 0.1f) * (1.0f / 7.0f);
            const float bh = fmaxf(roi[4] * SSCALE - y1, 0.1f) * (1.0f / 7.0f);

            float y = y1 + ((float)ph + sy) * bh;
            y = fminf(fmaxf(y, 0.0f), 127.0f);
            float y0f = floorf(y);
            int   y0  = (int)y0f;
            float ly  = y - y0f;
            if (y0 > 126) { y0 = 126; ly = 1.0f; }   // y==127 -> full weight on row 127

            float x = x1 + ((float)pw + sx) * bw;
            x = fminf(fmaxf(x, 0.0f), 127.0f);
            float x0f = floorf(x);
            int   x0  = (int)x0f;
            float lx  = x - x0f;
            if (x0 > 126) { x0 = 126; lx = 1.0f; }

            const float* p = plane + y0 * FW + x0;
            const float v00 = p[0];
            const float v01 = p[1];
            const float v10 = p[FW];
            const float v11 = p[FW + 1];

            const float top = v00 + (v01 - v00) * lx;
            const float bot = v10 + (v11 - v10) * lx;
            float val = top + (bot - top) * ly;

            val += __shfl_xor(val, 1);
            val += __shfl_xor(val, 2);
            if (sub == 0) out[(size_t)ri * CPLANE + c_in] = val * 0.25f;
        }
    }
}

extern "C" void kernel_launch(void* const* d_in, const int* in_sizes, int n_in,
                              void* d_out, int out_size, void* d_ws, size_t ws_size,
                              hipStream_t stream) {
    const float* feat = (const float*)d_in[0];
    const float* rois = (const float*)d_in[1];
    float* out = (float*)d_out;
    int* ws = (int*)d_ws;

    const int R = in_sizes[1] / 5;   // 2048

    bucket_rois<<<1, 1024, 0, stream>>>(rois, R, ws);
    psroi_plane_lds<<<NPLANES, 1024, 0, stream>>>(feat, rois, ws, out, R);
}